// Round 6
// baseline (170.398 us; speedup 1.0000x reference)
//
#include <hip/hip_runtime.h>

#define N_NODES 512
#define N_EDGES (512 * 512)

typedef _Float16 f16x8 __attribute__((ext_vector_type(8)));
typedef float f32x4 __attribute__((ext_vector_type(4)));

__device__ __forceinline__ unsigned pkf16(float a, float b) {
  return __builtin_bit_cast(unsigned, __builtin_amdgcn_cvt_pkrtz(a, b));
}

// ---------------- histogram of dst ----------------
__global__ void hist_k(const int* __restrict__ dst, int* __restrict__ counts) {
  __shared__ int lh[N_NODES];
  for (int i = threadIdx.x; i < N_NODES; i += blockDim.x) lh[i] = 0;
  __syncthreads();
  const int stride = gridDim.x * blockDim.x;
  for (int e = blockIdx.x * blockDim.x + threadIdx.x; e < N_EDGES; e += stride)
    atomicAdd(&lh[dst[e]], 1);
  __syncthreads();
  for (int i = threadIdx.x; i < N_NODES; i += blockDim.x) {
    int c = lh[i];
    if (c) atomicAdd(&counts[i], c);
  }
}

// ---------------- exclusive scan over 512 counts ----------------
__global__ void scan_k(const int* __restrict__ counts, int* __restrict__ offsets,
                       int* __restrict__ cursor) {
  __shared__ int tmp[N_NODES];
  const int t = threadIdx.x;
  const int c = counts[t];
  tmp[t] = c;
  __syncthreads();
  for (int d = 1; d < N_NODES; d <<= 1) {
    int add = (t >= d) ? tmp[t - d] : 0;
    __syncthreads();
    tmp[t] += add;
    __syncthreads();
  }
  offsets[t + 1] = tmp[t];
  if (t == 0) offsets[0] = 0;
  cursor[t] = tmp[t] - c;
}

// ---- scatter: CSR-sort edges, writing PACKED f16 ea (+bias-enable) and src ----
__launch_bounds__(512)
__global__ void scatter3_k(const float* __restrict__ ea, const int* __restrict__ src,
                           const int* __restrict__ dst, int* __restrict__ cursor,
                           uint4* __restrict__ eaPk, int* __restrict__ srcSorted) {
  __shared__ int lhist[N_NODES];
  __shared__ int gb[N_NODES];
  const int t = threadIdx.x;
  const int c0 = blockIdx.x * 4096;
  lhist[t] = 0;
  __syncthreads();
  int d[8], r[8];
#pragma unroll
  for (int j = 0; j < 8; j++) {
    d[j] = dst[c0 + t + j * 512];
    r[j] = atomicAdd(&lhist[d[j]], 1);
  }
  __syncthreads();
  gb[t] = atomicAdd(&cursor[t], lhist[t]);
  __syncthreads();
#pragma unroll
  for (int j = 0; j < 8; j++) {
    const int e = c0 + t + j * 512;
    const int pos = gb[d[j]] + r[j];
    const float2* er = reinterpret_cast<const float2*>(ea + (size_t)e * 6);
    const float2 a0 = er[0], a1 = er[1], a2 = er[2];
    uint4 pk;
    pk.x = pkf16(a0.x, a0.y);
    pk.y = pkf16(a1.x, a1.y);
    pk.z = pkf16(a2.x, a2.y);
    pk.w = 0x00003C00u;  // k=6 slot: (1.0h, 0h) -> enables bias row of W
    eaPk[pos] = pk;
    srcSorted[pos] = src[e];
  }
}

// ---------------- pack W(+bias) as MFMA A-operand rows: f16 k=0..5 W, k=6 bias ----
__global__ void packW_k(const float* __restrict__ W, const float* __restrict__ bvec,
                        uint4* __restrict__ out, int npair, int npad) {
  int p = blockIdx.x * 256 + threadIdx.x;
  if (p < npad) {
    uint4 r = make_uint4(0u, 0u, 0u, 0u);
    if (p < npair) {
      r.x = pkf16(W[0 * npair + p], W[1 * npair + p]);
      r.y = pkf16(W[2 * npair + p], W[3 * npair + p]);
      r.z = pkf16(W[4 * npair + p], W[5 * npair + p]);
      r.w = pkf16(bvec[p], 0.f);
    }
    out[p] = r;
  }
}

// ---------------- MFMA-fused NNConv layer ----------------
// Per node block (512 thr = 8 waves). theta tile = mfma16x16x32_f16(Wt, eaT):
//   A: lane<16 holds row p=tile*16+lane, k=0..5 (W), k=6 (bias); others zero.
//   B: lane<16 holds col e, k=0..5 (ea f16), k=6 (1.0 real / 0 pad); others zero.
//   C: col e = lane&15, row p_local = (lane>>4)*4 + reg   [m89-verified layout]
// Post: acc += relu(theta) * h[src_e, p/OUT]; reduce over 16 col-lanes; epilogue.
template <int IN, int OUT, int NT>
__launch_bounds__(512, 4)
__global__ void convM_k(const float* __restrict__ hprev,        // [N][IN] f32
                        const uint4* __restrict__ eaPk,         // [E] CSR-sorted
                        const int* __restrict__ srcSorted,      // [E] CSR-sorted
                        const int* __restrict__ offsets,        // [N+1]
                        const uint4* __restrict__ Wpk,          // [NT*16]
                        const float* __restrict__ root, const float* __restrict__ bias,
                        float* __restrict__ hnext) {            // [N][OUT]
  constexpr int NPAIR = IN * OUT;
  constexpr int TPW = (NT + 7) / 8;
  constexpr int CHUNK = 512;
  constexpr int NIV = (OUT % 4 == 0) ? 1 : 4;

  __shared__ uint4 eaS[2][CHUNK];
  __shared__ int srcS[2][CHUNK];
  __shared__ float pAcc[NPAIR];

  const int tid = threadIdx.x;
  const int w = tid >> 6;
  const int l = tid & 63;
  const int node = blockIdx.x;
  const int off = offsets[node];
  const int cnt = offsets[node + 1] - off;
  const int crow = (l >> 4) << 2;

  f16x8 afr[TPW];
  f32x4 acc[TPW];
  int iv[TPW][NIV];
#pragma unroll
  for (int j = 0; j < TPW; j++) {
    const int t = w + 8 * j;
    uint4 wv = make_uint4(0u, 0u, 0u, 0u);
    if (t < NT && l < 16) wv = Wpk[t * 16 + l];
    afr[j] = __builtin_bit_cast(f16x8, wv);
    acc[j] = (f32x4){0.f, 0.f, 0.f, 0.f};
#pragma unroll
    for (int r = 0; r < NIV; r++) iv[j][r] = min(t * 16 + crow + r, NPAIR - 1) / OUT;
  }

  const int NC = (cnt + CHUNK - 1) / CHUNK;
  uint4 lea = make_uint4(0u, 0u, 0u, 0u);
  int lsrc = 0;

  auto sload = [&](int c) {
    const int pos = c * CHUNK + tid;
    if (pos < cnt) {
      lea = eaPk[off + pos];
      lsrc = srcSorted[off + pos];
    } else {
      lea = make_uint4(0u, 0u, 0u, 0u);  // full-zero -> theta = relu(0) = 0
      lsrc = 0;
    }
  };
  auto swrite = [&](int b) {
    eaS[b][tid] = lea;
    srcS[b][tid] = lsrc;
  };

  sload(0);
  swrite(0);
  __syncthreads();

  const f32x4 zero4 = {0.f, 0.f, 0.f, 0.f};
  for (int c = 0; c < NC; c++) {
    const int b = c & 1;
    if (c + 1 < NC) sload(c + 1);
    const int lim = min(CHUNK, cnt - c * CHUNK);
    const int ntile = (lim + 15) >> 4;
    for (int et = 0; et < ntile; et++) {
      const int es = et * 16 + (l & 15);
      uint4 bv = eaS[b][es];
      const int s = srcS[b][es];
      if (l >= 16) bv = make_uint4(0u, 0u, 0u, 0u);
      const f16x8 bfr = __builtin_bit_cast(f16x8, bv);
      const float* hrow = hprev + (size_t)s * IN;
#pragma unroll
      for (int j = 0; j < TPW; j++) {
        f32x4 th = __builtin_amdgcn_mfma_f32_16x16x32_f16(afr[j], bfr, zero4, 0, 0, 0);
        if constexpr (NIV == 1) {
          const float hv = hrow[iv[j][0]];
#pragma unroll
          for (int r = 0; r < 4; r++) acc[j][r] = fmaf(fmaxf(th[r], 0.f), hv, acc[j][r]);
        } else {
#pragma unroll
          for (int r = 0; r < 4; r++)
            acc[j][r] = fmaf(fmaxf(th[r], 0.f), hrow[iv[j][r]], acc[j][r]);
        }
      }
    }
    if (c + 1 < NC) swrite((c + 1) & 1);
    __syncthreads();
  }

  // reduce each pair over the 16 col-lanes (same row-group), write pAcc
#pragma unroll
  for (int j = 0; j < TPW; j++) {
    const int t = w + 8 * j;
#pragma unroll
    for (int r = 0; r < 4; r++) {
      float v = acc[j][r];
      v += __shfl_xor(v, 1);
      v += __shfl_xor(v, 2);
      v += __shfl_xor(v, 4);
      v += __shfl_xor(v, 8);
      const int p = t * 16 + crow + r;
      if (t < NT && (l & 15) == 0 && p < NPAIR) pAcc[p] = v;
    }
  }
  __syncthreads();

  if (tid < OUT) {
    const int o = tid;
    float s = 0.f;
    for (int i = 0; i < IN; i++) s += pAcc[i * OUT + o];
    const float agg = s / fmaxf((float)cnt, 1.f);
    float r2 = bias[o];
    for (int i = 0; i < IN; i++)
      r2 = fmaf(hprev[(size_t)node * IN + i], root[i * OUT + o], r2);
    hnext[(size_t)node * OUT + o] = fmaxf(agg + r2, 0.f);
  }
}

// ---------------- CBT: pairwise L1 over h3 [512, 5] ----------------
__global__ void cbt_k(const float* __restrict__ h3, float* __restrict__ out) {
  __shared__ float sh[N_NODES * 5];
  for (int i = threadIdx.x; i < N_NODES * 5; i += blockDim.x) sh[i] = h3[i];
  __syncthreads();
  const int a = blockIdx.x;
  float ha0 = sh[a * 5 + 0], ha1 = sh[a * 5 + 1], ha2 = sh[a * 5 + 2],
        ha3 = sh[a * 5 + 3], ha4 = sh[a * 5 + 4];
  for (int b = threadIdx.x; b < N_NODES; b += blockDim.x) {
    float s = fabsf(sh[b * 5 + 0] - ha0) + fabsf(sh[b * 5 + 1] - ha1) +
              fabsf(sh[b * 5 + 2] - ha2) + fabsf(sh[b * 5 + 3] - ha3) +
              fabsf(sh[b * 5 + 4] - ha4);
    out[a * N_NODES + b] = s;
  }
}

extern "C" void kernel_launch(void* const* d_in, const int* in_sizes, int n_in,
                              void* d_out, int out_size, void* d_ws, size_t ws_size,
                              hipStream_t stream) {
  const float* x     = (const float*)d_in[0];
  const float* ea    = (const float*)d_in[1];
  const int*   ei    = (const int*)d_in[2];
  const float* W1    = (const float*)d_in[3];
  const float* b1    = (const float*)d_in[4];
  const float* root1 = (const float*)d_in[5];
  const float* bias1 = (const float*)d_in[6];
  const float* W2    = (const float*)d_in[7];
  const float* b2    = (const float*)d_in[8];
  const float* root2 = (const float*)d_in[9];
  const float* bias2 = (const float*)d_in[10];
  const float* W3    = (const float*)d_in[11];
  const float* b3    = (const float*)d_in[12];
  const float* root3 = (const float*)d_in[13];
  const float* bias3 = (const float*)d_in[14];

  const int* src = ei;
  const int* dst = ei + N_EDGES;

  char* ws = (char*)d_ws;
  int* counts    = (int*)(ws + 0);                  // 2 KB
  int* offsets   = (int*)(ws + 4096);               // 513 ints
  int* cursor    = (int*)(ws + 8192);               // 512 ints
  uint4* eaPk    = (uint4*)(ws + 16384);            // E * 16 B = 4 MB
  int* srcSorted = (int*)(ws + 16384 + N_EDGES * 16);            // 1 MB
  char* p2       = ws + 16384 + N_EDGES * 20;
  float* h1      = (float*)(p2);                    // 512*36
  float* h2_     = h1 + N_NODES * 36;               // 512*24
  float* h3      = h2_ + N_NODES * 24;              // 512*5
  uint4* wpk1    = (uint4*)(p2 + 256 * 1024);       // 48
  uint4* wpk2    = wpk1 + 48;                       // 864
  uint4* wpk3    = wpk2 + 864;                      // 128

  hipMemsetAsync(counts, 0, N_NODES * sizeof(int), stream);
  hist_k<<<256, 256, 0, stream>>>(dst, counts);
  scan_k<<<1, N_NODES, 0, stream>>>(counts, offsets, cursor);
  scatter3_k<<<N_EDGES / 4096, 512, 0, stream>>>(ea, src, dst, cursor, eaPk, srcSorted);
  packW_k<<<1, 256, 0, stream>>>(W1, b1, wpk1, 36, 48);
  packW_k<<<4, 256, 0, stream>>>(W2, b2, wpk2, 864, 864);
  packW_k<<<1, 256, 0, stream>>>(W3, b3, wpk3, 120, 128);

  convM_k<1, 36, 3><<<N_NODES, 512, 0, stream>>>(x, eaPk, srcSorted, offsets, wpk1, root1, bias1, h1);
  convM_k<36, 24, 54><<<N_NODES, 512, 0, stream>>>(h1, eaPk, srcSorted, offsets, wpk2, root2, bias2, h2_);
  convM_k<24, 5, 8><<<N_NODES, 512, 0, stream>>>(h2_, eaPk, srcSorted, offsets, wpk3, root3, bias3, h3);

  cbt_k<<<N_NODES, 256, 0, stream>>>(h3, (float*)d_out);
}

// Round 7
// 166.699 us; speedup vs baseline: 1.0222x; 1.0222x over previous
//
#include <hip/hip_runtime.h>

#define N_NODES 512
#define N_EDGES (512 * 512)

typedef _Float16 f16x8 __attribute__((ext_vector_type(8)));
typedef _Float16 f16x2 __attribute__((ext_vector_type(2)));
typedef float f32x4 __attribute__((ext_vector_type(4)));

__device__ __forceinline__ unsigned pkf16(float a, float b) {
  return __builtin_bit_cast(unsigned, __builtin_amdgcn_cvt_pkrtz(a, b));
}

// ---------------- histogram of dst ----------------
__global__ void hist_k(const int* __restrict__ dst, int* __restrict__ counts) {
  __shared__ int lh[N_NODES];
  for (int i = threadIdx.x; i < N_NODES; i += blockDim.x) lh[i] = 0;
  __syncthreads();
  const int stride = gridDim.x * blockDim.x;
  for (int e = blockIdx.x * blockDim.x + threadIdx.x; e < N_EDGES; e += stride)
    atomicAdd(&lh[dst[e]], 1);
  __syncthreads();
  for (int i = threadIdx.x; i < N_NODES; i += blockDim.x) {
    int c = lh[i];
    if (c) atomicAdd(&counts[i], c);
  }
}

// ---------------- exclusive scan over 512 counts ----------------
__global__ void scan_k(const int* __restrict__ counts, int* __restrict__ offsets,
                       int* __restrict__ cursor) {
  __shared__ int tmp[N_NODES];
  const int t = threadIdx.x;
  const int c = counts[t];
  tmp[t] = c;
  __syncthreads();
  for (int d = 1; d < N_NODES; d <<= 1) {
    int add = (t >= d) ? tmp[t - d] : 0;
    __syncthreads();
    tmp[t] += add;
    __syncthreads();
  }
  offsets[t + 1] = tmp[t];
  if (t == 0) offsets[0] = 0;
  cursor[t] = tmp[t] - c;
}

// ---- scatter: CSR-sort edges, writing PACKED f16 ea (+bias-enable) and src ----
__launch_bounds__(512)
__global__ void scatter3_k(const float* __restrict__ ea, const int* __restrict__ src,
                           const int* __restrict__ dst, int* __restrict__ cursor,
                           uint4* __restrict__ eaPk, int* __restrict__ srcSorted) {
  __shared__ int lhist[N_NODES];
  __shared__ int gb[N_NODES];
  const int t = threadIdx.x;
  const int c0 = blockIdx.x * 4096;
  lhist[t] = 0;
  __syncthreads();
  int d[8], r[8];
#pragma unroll
  for (int j = 0; j < 8; j++) {
    d[j] = dst[c0 + t + j * 512];
    r[j] = atomicAdd(&lhist[d[j]], 1);
  }
  __syncthreads();
  gb[t] = atomicAdd(&cursor[t], lhist[t]);
  __syncthreads();
#pragma unroll
  for (int j = 0; j < 8; j++) {
    const int e = c0 + t + j * 512;
    const int pos = gb[d[j]] + r[j];
    const float2* er = reinterpret_cast<const float2*>(ea + (size_t)e * 6);
    const float2 a0 = er[0], a1 = er[1], a2 = er[2];
    uint4 pk;
    pk.x = pkf16(a0.x, a0.y);
    pk.y = pkf16(a1.x, a1.y);
    pk.z = pkf16(a2.x, a2.y);
    pk.w = 0x00003C00u;  // k=6 slot: (1.0h, 0h) -> enables bias row of W
    eaPk[pos] = pk;
    srcSorted[pos] = src[e];
  }
}

// ---------------- pack W(+bias) as MFMA A-operand rows: f16 k=0..5 W, k=6 bias ----
__global__ void packW_k(const float* __restrict__ W, const float* __restrict__ bvec,
                        uint4* __restrict__ out, int npair, int npad) {
  int p = blockIdx.x * 256 + threadIdx.x;
  if (p < npad) {
    uint4 r = make_uint4(0u, 0u, 0u, 0u);
    if (p < npair) {
      r.x = pkf16(W[0 * npair + p], W[1 * npair + p]);
      r.y = pkf16(W[2 * npair + p], W[3 * npair + p]);
      r.z = pkf16(W[4 * npair + p], W[5 * npair + p]);
      r.w = pkf16(bvec[p], 0.f);
    }
    out[p] = r;
  }
}

// ---------------- two-phase MFMA NNConv ----------------
// Per node block (512 thr = 8 waves), 16-edge groups, double-buffered theta LDS.
// P1: theta tile = mfma16x16x32_f16(W-tile, ea-tile); relu; pack f16;
//     ds_write_b64 into thetaS[e][pair] (row stride PSTR halves, PSTR%8==4).
// P2: wave w consumes edges 2w, 2w+1 (wave-uniform src!): lane reads its
//     K_PER contiguous theta halves + 2 coalesced h-row values; fma into acc.
// End: per-wave partials -> LDS (overlaying thetaS) -> pair sums -> epilogue.
template <int IN, int OUT, int NT, int K_PER, int PSTR>
__launch_bounds__(512, 2)
__global__ void convT_k(const float* __restrict__ hprev,    // [N][IN] f32
                        const uint4* __restrict__ eaPk,     // [E] CSR-sorted
                        const int* __restrict__ srcSorted,  // [E] CSR-sorted
                        const int* __restrict__ offsets,    // [N+1]
                        const uint4* __restrict__ Wpk,      // [NT*16]
                        const float* __restrict__ root, const float* __restrict__ bias,
                        float* __restrict__ hnext) {        // [N][OUT]
  constexpr int NPAIR = IN * OUT;
  constexpr int TPW = (NT + 7) / 8;
  constexpr int HALFB = 16 * PSTR * 2;  // bytes per theta buffer
  constexpr size_t SMSZ = (2 * HALFB > 8 * NPAIR * 4) ? (size_t)(2 * HALFB)
                                                      : (size_t)(8 * NPAIR * 4);
  __shared__ __align__(16) char sm[SMSZ];

  const int tid = threadIdx.x;
  const int w = tid >> 6;
  const int l = tid & 63;
  const int node = blockIdx.x;
  const int off = offsets[node];
  const int cnt = offsets[node + 1] - off;
  const int crow = (l >> 4) << 2;
  const int col = l & 15;

  // ---- A fragments (W tiles) ----
  f16x8 afr[TPW];
#pragma unroll
  for (int j = 0; j < TPW; j++) {
    const int t = w + 8 * j;
    uint4 wv = make_uint4(0u, 0u, 0u, 0u);
    if (t < NT && l < 16) wv = Wpk[t * 16 + l];
    afr[j] = __builtin_bit_cast(f16x8, wv);
  }

  // ---- P2 per-lane pair slice ----
  const int p0 = l * K_PER;
  const bool act = (p0 < NPAIR);
  const int i0 = act ? (p0 / OUT) : 0;
  const int i1 = (i0 + 1 < IN) ? i0 + 1 : IN - 1;
  const int kb = (i0 + 1) * OUT - p0;  // k < kb -> i0, else i1
  float acc[K_PER];
#pragma unroll
  for (int k = 0; k < K_PER; k++) acc[k] = 0.f;

  const int NG = (cnt + 15) >> 4;
  const f32x4 zero4 = {0.f, 0.f, 0.f, 0.f};

  auto P1 = [&](int g) {
    const int pos = g * 16 + l;
    uint4 bv = make_uint4(0u, 0u, 0u, 0u);
    if (l < 16 && pos < cnt) bv = eaPk[off + pos];
    const f16x8 bfr = __builtin_bit_cast(f16x8, bv);
    char* base = sm + (size_t)(g & 1) * HALFB + (size_t)col * (PSTR * 2) + crow * 2;
#pragma unroll
    for (int j = 0; j < TPW; j++) {
      const int t = w + 8 * j;
      if (t < NT) {
        f32x4 th = __builtin_amdgcn_mfma_f32_16x16x32_f16(afr[j], bfr, zero4, 0, 0, 0);
        uint2 pk;
        pk.x = pkf16(fmaxf(th[0], 0.f), fmaxf(th[1], 0.f));
        pk.y = pkf16(fmaxf(th[2], 0.f), fmaxf(th[3], 0.f));
        *reinterpret_cast<uint2*>(base + t * 32) = pk;
      }
    }
  };

  auto P2 = [&](int g) {
    const char* bbase = sm + (size_t)(g & 1) * HALFB;
#pragma unroll
    for (int j2 = 0; j2 < 2; j2++) {
      const int eL = 2 * w + j2;
      const int pos = g * 16 + eL;
      if (pos < cnt) {
        const int s = srcSorted[off + pos];  // wave-uniform
        const float* hrow = hprev + (size_t)s * IN;
        const float hv0 = hrow[i0];
        const float hv1 = (IN > 1) ? hrow[i1] : hv0;
        const char* row = bbase + (size_t)eL * (PSTR * 2);
        if (act) {
          if constexpr (K_PER == 16) {
            const f16x8 q0 = *reinterpret_cast<const f16x8*>(row + l * 32);
            const f16x8 q1 = *reinterpret_cast<const f16x8*>(row + l * 32 + 16);
#pragma unroll
            for (int k = 0; k < 8; k++)
              acc[k] = fmaf((float)q0[k], (k < kb) ? hv0 : hv1, acc[k]);
#pragma unroll
            for (int k = 8; k < 16; k++)
              acc[k] = fmaf((float)q1[k - 8], (k < kb) ? hv0 : hv1, acc[k]);
          } else if constexpr (K_PER == 2) {
            const f16x2 q = *reinterpret_cast<const f16x2*>(row + l * 4);
            acc[0] = fmaf((float)q[0], (0 < kb) ? hv0 : hv1, acc[0]);
            acc[1] = fmaf((float)q[1], (1 < kb) ? hv0 : hv1, acc[1]);
          } else {
            const _Float16 q = *reinterpret_cast<const _Float16*>(row + l * 2);
            acc[0] = fmaf((float)q, hv0, acc[0]);
          }
        }
      }
    }
  };

  if (NG > 0) P1(0);
  __syncthreads();
  for (int g = 1; g < NG; g++) {
    P1(g);
    P2(g - 1);
    __syncthreads();
  }
  if (NG > 0) P2(NG - 1);
  __syncthreads();

  // ---- reduction: per-wave partials (overlay theta LDS) ----
  float* pA = reinterpret_cast<float*>(sm);
  if (act) {
#pragma unroll
    for (int k = 0; k < K_PER; k++)
      if (p0 + k < NPAIR) pA[w * NPAIR + p0 + k] = acc[k];
  }
  __syncthreads();
  for (int p = tid; p < NPAIR; p += 512) {
    float s = 0.f;
#pragma unroll
    for (int ww = 0; ww < 8; ww++) s += pA[ww * NPAIR + p];
    pA[p] = s;
  }
  __syncthreads();
  if (tid < OUT) {
    const int o = tid;
    float s = 0.f;
    for (int i = 0; i < IN; i++) s += pA[i * OUT + o];
    const float agg = s / fmaxf((float)cnt, 1.f);
    float r2 = bias[o];
    for (int i = 0; i < IN; i++)
      r2 = fmaf(hprev[(size_t)node * IN + i], root[i * OUT + o], r2);
    hnext[(size_t)node * OUT + o] = fmaxf(agg + r2, 0.f);
  }
}

// ---------------- CBT: pairwise L1 over h3 [512, 5] ----------------
__global__ void cbt_k(const float* __restrict__ h3, float* __restrict__ out) {
  __shared__ float sh[N_NODES * 5];
  for (int i = threadIdx.x; i < N_NODES * 5; i += blockDim.x) sh[i] = h3[i];
  __syncthreads();
  const int a = blockIdx.x;
  float ha0 = sh[a * 5 + 0], ha1 = sh[a * 5 + 1], ha2 = sh[a * 5 + 2],
        ha3 = sh[a * 5 + 3], ha4 = sh[a * 5 + 4];
  for (int b = threadIdx.x; b < N_NODES; b += blockDim.x) {
    float s = fabsf(sh[b * 5 + 0] - ha0) + fabsf(sh[b * 5 + 1] - ha1) +
              fabsf(sh[b * 5 + 2] - ha2) + fabsf(sh[b * 5 + 3] - ha3) +
              fabsf(sh[b * 5 + 4] - ha4);
    out[a * N_NODES + b] = s;
  }
}

extern "C" void kernel_launch(void* const* d_in, const int* in_sizes, int n_in,
                              void* d_out, int out_size, void* d_ws, size_t ws_size,
                              hipStream_t stream) {
  const float* x     = (const float*)d_in[0];
  const float* ea    = (const float*)d_in[1];
  const int*   ei    = (const int*)d_in[2];
  const float* W1    = (const float*)d_in[3];
  const float* b1    = (const float*)d_in[4];
  const float* root1 = (const float*)d_in[5];
  const float* bias1 = (const float*)d_in[6];
  const float* W2    = (const float*)d_in[7];
  const float* b2    = (const float*)d_in[8];
  const float* root2 = (const float*)d_in[9];
  const float* bias2 = (const float*)d_in[10];
  const float* W3    = (const float*)d_in[11];
  const float* b3    = (const float*)d_in[12];
  const float* root3 = (const float*)d_in[13];
  const float* bias3 = (const float*)d_in[14];

  const int* src = ei;
  const int* dst = ei + N_EDGES;

  char* ws = (char*)d_ws;
  int* counts    = (int*)(ws + 0);
  int* offsets   = (int*)(ws + 4096);
  int* cursor    = (int*)(ws + 8192);
  uint4* eaPk    = (uint4*)(ws + 16384);                 // 4 MB
  int* srcSorted = (int*)(ws + 16384 + N_EDGES * 16);    // 1 MB
  char* p2       = ws + 16384 + N_EDGES * 20;
  float* h1      = (float*)(p2);
  float* h2_     = h1 + N_NODES * 36;
  float* h3      = h2_ + N_NODES * 24;
  uint4* wpk1    = (uint4*)(p2 + 256 * 1024);            // 48
  uint4* wpk2    = wpk1 + 48;                            // 864
  uint4* wpk3    = wpk2 + 864;                           // 128

  hipMemsetAsync(counts, 0, N_NODES * sizeof(int), stream);
  hist_k<<<64, 256, 0, stream>>>(dst, counts);
  scan_k<<<1, N_NODES, 0, stream>>>(counts, offsets, cursor);
  scatter3_k<<<N_EDGES / 4096, 512, 0, stream>>>(ea, src, dst, cursor, eaPk, srcSorted);
  packW_k<<<1, 256, 0, stream>>>(W1, b1, wpk1, 36, 48);
  packW_k<<<4, 256, 0, stream>>>(W2, b2, wpk2, 864, 864);
  packW_k<<<1, 256, 0, stream>>>(W3, b3, wpk3, 120, 128);

  // layer 1: IN=1 OUT=36 (NT=3, K_PER=1, PSTR=52)
  convT_k<1, 36, 3, 1, 52><<<N_NODES, 512, 0, stream>>>(x, eaPk, srcSorted, offsets, wpk1, root1, bias1, h1);
  // layer 2: IN=36 OUT=24 (NT=54, K_PER=16, PSTR=868)
  convT_k<36, 24, 54, 16, 868><<<N_NODES, 512, 0, stream>>>(h1, eaPk, srcSorted, offsets, wpk2, root2, bias2, h2_);
  // layer 3: IN=24 OUT=5 (NT=8, K_PER=2, PSTR=132)
  convT_k<24, 5, 8, 2, 132><<<N_NODES, 512, 0, stream>>>(h2_, eaPk, srcSorted, offsets, wpk3, root3, bias3, h3);

  cbt_k<<<N_NODES, 256, 0, stream>>>(h3, (float*)d_out);
}

// Round 8
// 152.704 us; speedup vs baseline: 1.1159x; 1.0916x over previous
//
#include <hip/hip_runtime.h>

#define N_NODES 512
#define N_EDGES (512 * 512)

typedef _Float16 f16x8 __attribute__((ext_vector_type(8)));
typedef float f32x4 __attribute__((ext_vector_type(4)));

__device__ __forceinline__ unsigned pkf16(float a, float b) {
  return __builtin_bit_cast(unsigned, __builtin_amdgcn_cvt_pkrtz(a, b));
}
// f32 acc += f16(lo/hi of u) * f32 h  — single VOP3P instr
__device__ __forceinline__ float fmix_lo(unsigned u, float b, float c) {
  float d;
  asm("v_fma_mix_f32 %0, %1, %2, %3 op_sel_hi:[1,0,0]" : "=v"(d) : "v"(u), "v"(b), "v"(c));
  return d;
}
__device__ __forceinline__ float fmix_hi(unsigned u, float b, float c) {
  float d;
  asm("v_fma_mix_f32 %0, %1, %2, %3 op_sel:[1,0,0] op_sel_hi:[1,0,0]" : "=v"(d) : "v"(u), "v"(b), "v"(c));
  return d;
}

// ---------------- histogram of dst ----------------
__global__ void hist_k(const int* __restrict__ dst, int* __restrict__ counts) {
  __shared__ int lh[N_NODES];
  for (int i = threadIdx.x; i < N_NODES; i += blockDim.x) lh[i] = 0;
  __syncthreads();
  const int stride = gridDim.x * blockDim.x;
  for (int e = blockIdx.x * blockDim.x + threadIdx.x; e < N_EDGES; e += stride)
    atomicAdd(&lh[dst[e]], 1);
  __syncthreads();
  for (int i = threadIdx.x; i < N_NODES; i += blockDim.x) {
    int c = lh[i];
    if (c) atomicAdd(&counts[i], c);
  }
}

// ---------------- exclusive scan over 512 counts ----------------
__global__ void scan_k(const int* __restrict__ counts, int* __restrict__ offsets,
                       int* __restrict__ cursor) {
  __shared__ int tmp[N_NODES];
  const int t = threadIdx.x;
  const int c = counts[t];
  tmp[t] = c;
  __syncthreads();
  for (int d = 1; d < N_NODES; d <<= 1) {
    int add = (t >= d) ? tmp[t - d] : 0;
    __syncthreads();
    tmp[t] += add;
    __syncthreads();
  }
  offsets[t + 1] = tmp[t];
  if (t == 0) offsets[0] = 0;
  cursor[t] = tmp[t] - c;
}

// ---- scatter: CSR-sort edges, writing PACKED f16 ea (+bias-enable) and src ----
__launch_bounds__(512)
__global__ void scatter3_k(const float* __restrict__ ea, const int* __restrict__ src,
                           const int* __restrict__ dst, int* __restrict__ cursor,
                           uint4* __restrict__ eaPk, int* __restrict__ srcSorted) {
  __shared__ int lhist[N_NODES];
  __shared__ int gb[N_NODES];
  const int t = threadIdx.x;
  const int c0 = blockIdx.x * 4096;
  lhist[t] = 0;
  __syncthreads();
  int d[8], r[8];
#pragma unroll
  for (int j = 0; j < 8; j++) {
    d[j] = dst[c0 + t + j * 512];
    r[j] = atomicAdd(&lhist[d[j]], 1);
  }
  __syncthreads();
  gb[t] = atomicAdd(&cursor[t], lhist[t]);
  __syncthreads();
#pragma unroll
  for (int j = 0; j < 8; j++) {
    const int e = c0 + t + j * 512;
    const int pos = gb[d[j]] + r[j];
    const float2* er = reinterpret_cast<const float2*>(ea + (size_t)e * 6);
    const float2 a0 = er[0], a1 = er[1], a2 = er[2];
    uint4 pk;
    pk.x = pkf16(a0.x, a0.y);
    pk.y = pkf16(a1.x, a1.y);
    pk.z = pkf16(a2.x, a2.y);
    pk.w = 0x00003C00u;  // k=6: (1.0h, 0h) -> bias row enable
    eaPk[pos] = pk;
    srcSorted[pos] = src[e];
  }
}

// ------- pack all 3 layers' W(+bias) as MFMA A-rows in ONE launch ----------
__device__ __forceinline__ void packOne(const float* W, const float* b, uint4* out,
                                        int npair, int idx) {
  uint4 r = make_uint4(0u, 0u, 0u, 0u);
  if (idx < npair) {
    r.x = pkf16(W[0 * npair + idx], W[1 * npair + idx]);
    r.y = pkf16(W[2 * npair + idx], W[3 * npair + idx]);
    r.z = pkf16(W[4 * npair + idx], W[5 * npair + idx]);
    r.w = pkf16(b[idx], 0.f);
  }
  out[idx >= npair ? idx : idx] = r;  // idx < npad always
}
__global__ void packAll_k(const float* __restrict__ W1, const float* __restrict__ b1,
                          const float* __restrict__ W2, const float* __restrict__ b2,
                          const float* __restrict__ W3, const float* __restrict__ b3,
                          uint4* __restrict__ wpk) {
  int t = blockIdx.x * 256 + threadIdx.x;  // 0..1039
  if (t < 48) {
    uint4 r = make_uint4(0u, 0u, 0u, 0u);
    if (t < 36) {
      r.x = pkf16(W1[0 * 36 + t], W1[1 * 36 + t]);
      r.y = pkf16(W1[2 * 36 + t], W1[3 * 36 + t]);
      r.z = pkf16(W1[4 * 36 + t], W1[5 * 36 + t]);
      r.w = pkf16(b1[t], 0.f);
    }
    wpk[t] = r;
  } else if (t < 48 + 864) {
    int p = t - 48;
    uint4 r;
    r.x = pkf16(W2[0 * 864 + p], W2[1 * 864 + p]);
    r.y = pkf16(W2[2 * 864 + p], W2[3 * 864 + p]);
    r.z = pkf16(W2[4 * 864 + p], W2[5 * 864 + p]);
    r.w = pkf16(b2[p], 0.f);
    wpk[t] = r;
  } else if (t < 48 + 864 + 128) {
    int p = t - 912;
    uint4 r = make_uint4(0u, 0u, 0u, 0u);
    if (p < 120) {
      r.x = pkf16(W3[0 * 120 + p], W3[1 * 120 + p]);
      r.y = pkf16(W3[2 * 120 + p], W3[3 * 120 + p]);
      r.z = pkf16(W3[4 * 120 + p], W3[5 * 120 + p]);
      r.w = pkf16(b3[p], 0.f);
    }
    wpk[t] = r;
  }
}

// ---------------- two-phase MFMA NNConv, row-rotated theta LDS ----------------
// theta chunk (edge e, tile t) lives at physical row (e+t+(t>>4))&15, byte t*32.
// P1: mfma -> relu -> pack f16 -> ds_write_b64 (rotated rows: ~2-4-way banks).
// P2 (UNIF, OUT==K_PER): lane = input channel i; 3x ds_read_b128 of its 24
//    thetas (rotated rows -> ~2-way); 24x v_fma_mix_f32 with coalesced h[s][i].
// P2 (generic): per-lane K_PER pairs, scalar cvt+fma.
template <int IN, int OUT, int NT, int K_PER, int ROWB>
__launch_bounds__(512, 4)
__global__ void convT2_k(const float* __restrict__ hprev,    // [N][IN] f32
                         const uint4* __restrict__ eaPk,     // [E] CSR-sorted
                         const int* __restrict__ srcSorted,  // [E]
                         const int* __restrict__ offsets,    // [N+1]
                         const uint4* __restrict__ Wpk,      // [NT*16]
                         const float* __restrict__ root, const float* __restrict__ bias,
                         float* __restrict__ hnext) {        // [N][OUT]
  constexpr int NPAIR = IN * OUT;
  constexpr int TPW = (NT + 7) / 8;
  constexpr bool UNIF = (K_PER == OUT);
  constexpr int HALF = 16 * ROWB;
  constexpr size_t SMSZ = (2 * HALF > 8 * NPAIR * 4) ? (size_t)(2 * HALF)
                                                     : (size_t)(8 * NPAIR * 4);
  __shared__ __align__(16) char sm[SMSZ];

  const int tid = threadIdx.x;
  const int w = tid >> 6;
  const int l = tid & 63;
  const int node = blockIdx.x;
  const int off = offsets[node];
  const int cnt = offsets[node + 1] - off;
  const int crow = (l >> 4) << 2;
  const int eloc = l & 15;

  // ---- A fragments (W tiles) ----
  f16x8 afr[TPW];
#pragma unroll
  for (int j = 0; j < TPW; j++) {
    const int t = w + 8 * j;
    uint4 wv = make_uint4(0u, 0u, 0u, 0u);
    if (t < NT && l < 16) wv = Wpk[t * 16 + l];
    afr[j] = __builtin_bit_cast(f16x8, wv);
  }

  // ---- P2 per-lane slice ----
  const int p0 = l * K_PER;
  const bool act = (p0 < NPAIR);
  const int i0 = act ? (p0 / OUT) : 0;
  const int i1 = (i0 + 1 < IN) ? i0 + 1 : IN - 1;
  const int kb = (i0 + 1) * OUT - p0;
  float acc[K_PER];
#pragma unroll
  for (int k = 0; k < K_PER; k++) acc[k] = 0.f;

  const int NG = (cnt + 15) >> 4;
  const f32x4 zero4 = {0.f, 0.f, 0.f, 0.f};

  auto P1 = [&](int g) {
    const int pos = g * 16 + l;
    uint4 bv = make_uint4(0u, 0u, 0u, 0u);
    if (l < 16 && pos < cnt) bv = eaPk[off + pos];
    const f16x8 bfr = __builtin_bit_cast(f16x8, bv);
    char* base = sm + (size_t)(g & 1) * HALF;
#pragma unroll
    for (int j = 0; j < TPW; j++) {
      const int t = w + 8 * j;
      if (t < NT) {
        f32x4 th = __builtin_amdgcn_mfma_f32_16x16x32_f16(afr[j], bfr, zero4, 0, 0, 0);
        uint2 pk;
        pk.x = pkf16(fmaxf(th[0], 0.f), fmaxf(th[1], 0.f));
        pk.y = pkf16(fmaxf(th[2], 0.f), fmaxf(th[3], 0.f));
        const int row = (eloc + t + (t >> 4)) & 15;
        *reinterpret_cast<uint2*>(base + row * ROWB + t * 32 + crow * 2) = pk;
      }
    }
  };

  auto P2 = [&](int g) {
    const char* bbase = sm + (size_t)(g & 1) * HALF;
#pragma unroll
    for (int j2 = 0; j2 < 2; j2++) {
      const int eL = 2 * w + j2;
      const int pos = g * 16 + eL;
      if (pos < cnt && act) {
        const int s = srcSorted[off + pos];  // wave-uniform
        const float* hrow = hprev + (size_t)s * IN;
        if constexpr (UNIF) {
          // lane = i, 24 pairs, 3 aligned b128 reads from rotated rows
          const float hv = hrow[l];  // coalesced
          unsigned q[12];
#pragma unroll
          for (int sgi = 0; sgi < 3; sgi++) {
            const int sb = p0 * 2 + 16 * sgi;
            const int t = sb >> 5;
            const int row = (eL + t + (t >> 4)) & 15;
            *reinterpret_cast<uint4*>(&q[4 * sgi]) =
                *reinterpret_cast<const uint4*>(bbase + row * ROWB + (t << 5) + (sb & 31));
          }
#pragma unroll
          for (int o = 0; o < OUT; o += 2) {
            acc[o] = fmix_lo(q[o >> 1], hv, acc[o]);
            acc[o + 1] = fmix_hi(q[o >> 1], hv, acc[o + 1]);
          }
        } else {
          const float hv0 = hrow[i0];
          const float hv1 = (IN > 1) ? hrow[i1] : hv0;
          const int t = p0 >> 4;
          const int row = (eL + t + (t >> 4)) & 15;
          const char* ptr = bbase + row * ROWB + t * 32 + (p0 & 15) * 2;
          if constexpr (K_PER == 2) {
            const unsigned q = *reinterpret_cast<const unsigned*>(ptr);
            acc[0] = fmix_lo(q, (0 < kb) ? hv0 : hv1, acc[0]);
            acc[1] = fmix_hi(q, (1 < kb) ? hv0 : hv1, acc[1]);
          } else {
            const unsigned short q = *reinterpret_cast<const unsigned short*>(ptr);
            acc[0] = fmix_lo((unsigned)q, hv0, acc[0]);
          }
        }
      }
    }
  };

  if (NG > 0) P1(0);
  __syncthreads();
  for (int g = 1; g < NG; g++) {
    P1(g);
    P2(g - 1);
    __syncthreads();
  }
  if (NG > 0) P2(NG - 1);
  __syncthreads();

  // ---- reduction: per-wave partials (overlay theta LDS) ----
  float* pA = reinterpret_cast<float*>(sm);
  if (act) {
#pragma unroll
    for (int k = 0; k < K_PER; k++)
      if (p0 + k < NPAIR) pA[w * NPAIR + p0 + k] = acc[k];
  }
  __syncthreads();
  for (int p = tid; p < NPAIR; p += 512) {
    float s = 0.f;
#pragma unroll
    for (int ww = 0; ww < 8; ww++) s += pA[ww * NPAIR + p];
    pA[p] = s;
  }
  __syncthreads();
  if (tid < OUT) {
    const int o = tid;
    float s = 0.f;
    for (int i = 0; i < IN; i++) s += pA[i * OUT + o];
    const float agg = s / fmaxf((float)cnt, 1.f);
    float r2 = bias[o];
    for (int i = 0; i < IN; i++)
      r2 = fmaf(hprev[(size_t)node * IN + i], root[i * OUT + o], r2);
    hnext[(size_t)node * OUT + o] = fmaxf(agg + r2, 0.f);
  }
}

// ---------------- CBT: pairwise L1 over h3 [512, 5] ----------------
__global__ void cbt_k(const float* __restrict__ h3, float* __restrict__ out) {
  __shared__ float sh[N_NODES * 5];
  for (int i = threadIdx.x; i < N_NODES * 5; i += blockDim.x) sh[i] = h3[i];
  __syncthreads();
  const int a = blockIdx.x;
  float ha0 = sh[a * 5 + 0], ha1 = sh[a * 5 + 1], ha2 = sh[a * 5 + 2],
        ha3 = sh[a * 5 + 3], ha4 = sh[a * 5 + 4];
  for (int b = threadIdx.x; b < N_NODES; b += blockDim.x) {
    float s = fabsf(sh[b * 5 + 0] - ha0) + fabsf(sh[b * 5 + 1] - ha1) +
              fabsf(sh[b * 5 + 2] - ha2) + fabsf(sh[b * 5 + 3] - ha3) +
              fabsf(sh[b * 5 + 4] - ha4);
    out[a * N_NODES + b] = s;
  }
}

extern "C" void kernel_launch(void* const* d_in, const int* in_sizes, int n_in,
                              void* d_out, int out_size, void* d_ws, size_t ws_size,
                              hipStream_t stream) {
  const float* x     = (const float*)d_in[0];
  const float* ea    = (const float*)d_in[1];
  const int*   ei    = (const int*)d_in[2];
  const float* W1    = (const float*)d_in[3];
  const float* b1    = (const float*)d_in[4];
  const float* root1 = (const float*)d_in[5];
  const float* bias1 = (const float*)d_in[6];
  const float* W2    = (const float*)d_in[7];
  const float* b2    = (const float*)d_in[8];
  const float* root2 = (const float*)d_in[9];
  const float* bias2 = (const float*)d_in[10];
  const float* W3    = (const float*)d_in[11];
  const float* b3    = (const float*)d_in[12];
  const float* root3 = (const float*)d_in[13];
  const float* bias3 = (const float*)d_in[14];

  const int* src = ei;
  const int* dst = ei + N_EDGES;

  char* ws = (char*)d_ws;
  int* counts    = (int*)(ws + 0);
  int* offsets   = (int*)(ws + 4096);
  int* cursor    = (int*)(ws + 8192);
  uint4* eaPk    = (uint4*)(ws + 16384);                 // 4 MB
  int* srcSorted = (int*)(ws + 16384 + N_EDGES * 16);    // 1 MB
  char* p2       = ws + 16384 + N_EDGES * 20;
  float* h1      = (float*)(p2);
  float* h2_     = h1 + N_NODES * 36;
  float* h3      = h2_ + N_NODES * 24;
  uint4* wpkAll  = (uint4*)(p2 + 256 * 1024);            // 1040 uint4
  uint4* wpk1    = wpkAll;                               // 48
  uint4* wpk2    = wpkAll + 48;                          // 864
  uint4* wpk3    = wpkAll + 912;                         // 128

  hipMemsetAsync(counts, 0, N_NODES * sizeof(int), stream);
  hist_k<<<64, 256, 0, stream>>>(dst, counts);
  scan_k<<<1, N_NODES, 0, stream>>>(counts, offsets, cursor);
  scatter3_k<<<N_EDGES / 4096, 512, 0, stream>>>(ea, src, dst, cursor, eaPk, srcSorted);
  packAll_k<<<5, 256, 0, stream>>>(W1, b1, W2, b2, W3, b3, wpkAll);

  // layer 1: IN=1 OUT=36 (NT=3, K_PER=1, ROWB=112)
  convT2_k<1, 36, 3, 1, 112><<<N_NODES, 512, 0, stream>>>(x, eaPk, srcSorted, offsets, wpk1, root1, bias1, h1);
  // layer 2: IN=36 OUT=24 (NT=54, K_PER=24 -> UNIF lane-per-i path, ROWB=1744)
  convT2_k<36, 24, 54, 24, 1744><<<N_NODES, 512, 0, stream>>>(h1, eaPk, srcSorted, offsets, wpk2, root2, bias2, h2_);
  // layer 3: IN=24 OUT=5 (NT=8, K_PER=2, ROWB=272)
  convT2_k<24, 5, 8, 2, 272><<<N_NODES, 512, 0, stream>>>(h2_, eaPk, srcSorted, offsets, wpk3, root3, bias3, h3);

  cbt_k<<<N_NODES, 256, 0, stream>>>(h3, (float*)d_out);
}

// Round 9
// 99.703 us; speedup vs baseline: 1.7091x; 1.5316x over previous
//
#include <hip/hip_runtime.h>

#define N_NODES 512
#define N_EDGES (512 * 512)

typedef _Float16 f16x8 __attribute__((ext_vector_type(8)));
typedef float f32x4 __attribute__((ext_vector_type(4)));

__device__ __forceinline__ unsigned pkf16(float a, float b) {
  return __builtin_bit_cast(unsigned, __builtin_amdgcn_cvt_pkrtz(a, b));
}

// ---------------- histogram of dst ----------------
__global__ void hist_k(const int* __restrict__ dst, int* __restrict__ counts) {
  __shared__ int lh[N_NODES];
  for (int i = threadIdx.x; i < N_NODES; i += blockDim.x) lh[i] = 0;
  __syncthreads();
  const int stride = gridDim.x * blockDim.x;
  for (int e = blockIdx.x * blockDim.x + threadIdx.x; e < N_EDGES; e += stride)
    atomicAdd(&lh[dst[e]], 1);
  __syncthreads();
  for (int i = threadIdx.x; i < N_NODES; i += blockDim.x) {
    int c = lh[i];
    if (c) atomicAdd(&counts[i], c);
  }
}

// ---------------- exclusive scan over 512 counts ----------------
__global__ void scan_k(const int* __restrict__ counts, int* __restrict__ offsets,
                       int* __restrict__ cursor) {
  __shared__ int tmp[N_NODES];
  const int t = threadIdx.x;
  const int c = counts[t];
  tmp[t] = c;
  __syncthreads();
  for (int d = 1; d < N_NODES; d <<= 1) {
    int add = (t >= d) ? tmp[t - d] : 0;
    __syncthreads();
    tmp[t] += add;
    __syncthreads();
  }
  offsets[t + 1] = tmp[t];
  if (t == 0) offsets[0] = 0;
  cursor[t] = tmp[t] - c;
}

// ---- scatter: CSR-sort edges, writing PACKED f16 ea (+bias-enable) and src ----
__launch_bounds__(512)
__global__ void scatter3_k(const float* __restrict__ ea, const int* __restrict__ src,
                           const int* __restrict__ dst, int* __restrict__ cursor,
                           uint4* __restrict__ eaPk, int* __restrict__ srcSorted) {
  __shared__ int lhist[N_NODES];
  __shared__ int gb[N_NODES];
  const int t = threadIdx.x;
  const int c0 = blockIdx.x * 4096;
  lhist[t] = 0;
  __syncthreads();
  int d[8], r[8];
#pragma unroll
  for (int j = 0; j < 8; j++) {
    d[j] = dst[c0 + t + j * 512];
    r[j] = atomicAdd(&lhist[d[j]], 1);
  }
  __syncthreads();
  gb[t] = atomicAdd(&cursor[t], lhist[t]);
  __syncthreads();
#pragma unroll
  for (int j = 0; j < 8; j++) {
    const int e = c0 + t + j * 512;
    const int pos = gb[d[j]] + r[j];
    const float2* er = reinterpret_cast<const float2*>(ea + (size_t)e * 6);
    const float2 a0 = er[0], a1 = er[1], a2 = er[2];
    uint4 pk;
    pk.x = pkf16(a0.x, a0.y);
    pk.y = pkf16(a1.x, a1.y);
    pk.z = pkf16(a2.x, a2.y);
    pk.w = 0x00003C00u;  // k=6: (1.0h, 0h) -> bias row enable
    eaPk[pos] = pk;
    srcSorted[pos] = src[e];
  }
}

// ---- pack W+bias as MFMA A-rows, i-uniform padded tile layouts, one launch ----
// L1 (t in [0,48)):    p_pad = t; o = t; valid o<36 (i=0)
// L2 (t in [48,1200)): q = t-48; tile=q/16, row=q%16, i=tile/2, o=(tile&1)*16+row; valid o<24
// L3 (t in [1200,1328)): q = t-1200; tile=q/16, row=q%16; i=3*tile+row/5, o=row%5; valid row<15
__global__ void packAll2_k(const float* __restrict__ W1, const float* __restrict__ b1,
                           const float* __restrict__ W2, const float* __restrict__ b2,
                           const float* __restrict__ W3, const float* __restrict__ b3,
                           uint4* __restrict__ wpk) {
  const int t = blockIdx.x * 256 + threadIdx.x;
  uint4 r = make_uint4(0u, 0u, 0x00000000u, pkf16(-1.f, 0.f));  // pad: w=0, bias=-1
  if (t < 48) {
    if (t < 36) {
      r.x = pkf16(W1[0 * 36 + t], W1[1 * 36 + t]);
      r.y = pkf16(W1[2 * 36 + t], W1[3 * 36 + t]);
      r.z = pkf16(W1[4 * 36 + t], W1[5 * 36 + t]);
      r.w = pkf16(b1[t], 0.f);
    }
    wpk[t] = r;
  } else if (t < 1200) {
    const int q = t - 48;
    const int tile = q >> 4, row = q & 15;
    const int i = tile >> 1, o = ((tile & 1) << 4) + row;
    if (o < 24) {
      const int p = i * 24 + o;
      r.x = pkf16(W2[0 * 864 + p], W2[1 * 864 + p]);
      r.y = pkf16(W2[2 * 864 + p], W2[3 * 864 + p]);
      r.z = pkf16(W2[4 * 864 + p], W2[5 * 864 + p]);
      r.w = pkf16(b2[p], 0.f);
    }
    wpk[t] = r;
  } else if (t < 1328) {
    const int q = t - 1200;
    const int tile = q >> 4, row = q & 15;
    if (row < 15) {
      const int i = 3 * tile + row / 5;
      const int o = row % 5;
      const int p = i * 5 + o;
      r.x = pkf16(W3[0 * 120 + p], W3[1 * 120 + p]);
      r.y = pkf16(W3[2 * 120 + p], W3[3 * 120 + p]);
      r.z = pkf16(W3[4 * 120 + p], W3[5 * 120 + p]);
      r.w = pkf16(b3[p], 0.f);
    }
    wpk[t] = r;
  }
}

// ======== layer 1: IN=1, OUT=36 (3 tiles, i=0). Wave-independent groups. ========
__launch_bounds__(512, 4)
__global__ void conv1_k(const float* __restrict__ x,        // [512][1]
                        const uint4* __restrict__ eaPk, const int* __restrict__ srcSorted,
                        const int* __restrict__ offsets, const uint4* __restrict__ Wpk,
                        const float* __restrict__ root,     // [1][36]
                        const float* __restrict__ bias,     // [36]
                        float* __restrict__ hnext) {        // [512][36]
  __shared__ float hS[N_NODES];
  __shared__ float pAcc[8][48];
  const int tid = threadIdx.x, w = tid >> 6, l = tid & 63;
  const int node = blockIdx.x;
  const int off = offsets[node], cnt = offsets[node + 1] - off;
  const int col = l & 15, crow = (l >> 4) << 2;

  if (tid < N_NODES) hS[tid] = x[tid];

  f16x8 afr[3];
  f32x4 acc[3];
#pragma unroll
  for (int t = 0; t < 3; t++) {
    uint4 wv = make_uint4(0u, 0u, 0u, 0u);
    if (l < 16) wv = Wpk[t * 16 + l];
    afr[t] = __builtin_bit_cast(f16x8, wv);
    acc[t] = (f32x4){0.f, 0.f, 0.f, 0.f};
  }
  __syncthreads();

  const int NG = (cnt + 15) >> 4;
  const f32x4 zero4 = {0.f, 0.f, 0.f, 0.f};
  for (int g = w; g < NG; g += 8) {
    const int pos = g * 16 + col;
    const bool v = pos < cnt;
    const int s = v ? srcSorted[off + pos] : 0;
    uint4 bv = make_uint4(0u, 0u, 0u, 0u);
    if (l < 16 && v) bv = eaPk[off + pos];
    const f16x8 bfr = __builtin_bit_cast(f16x8, bv);
    const float hv = hS[s];
#pragma unroll
    for (int t = 0; t < 3; t++) {
      f32x4 th = __builtin_amdgcn_mfma_f32_16x16x32_f16(afr[t], bfr, zero4, 0, 0, 0);
#pragma unroll
      for (int r = 0; r < 4; r++)
        acc[t][r] = fmaf(fmaxf(th[r], 0.f), hv, acc[t][r]);
    }
  }
#pragma unroll
  for (int t = 0; t < 3; t++)
#pragma unroll
    for (int r = 0; r < 4; r++) {
      float vv = acc[t][r];
      vv += __shfl_xor(vv, 1); vv += __shfl_xor(vv, 2);
      vv += __shfl_xor(vv, 4); vv += __shfl_xor(vv, 8);
      if (col == 0) pAcc[w][t * 16 + crow + r] = vv;
    }
  __syncthreads();
  if (tid < 36) {
    const int o = tid;
    float sagg = 0.f;
#pragma unroll
    for (int ww = 0; ww < 8; ww++) sagg += pAcc[ww][o];
    const float agg = sagg / fmaxf((float)cnt, 1.f);
    const float r2 = fmaf(hS[node], root[o], bias[o]);
    hnext[node * 36 + o] = fmaxf(agg + r2, 0.f);
  }
}

// ======== layer 2: IN=36, OUT=24 (72 padded tiles = 36 i-pairs). ========
// Full h table in LDS (stride 37). Waves split tile-pairs; share edge groups;
// NO barriers in main loop; theta stays in C-regs (no LDS round-trip).
__launch_bounds__(512, 4)
__global__ void conv2_k(const float* __restrict__ hprev,    // [512][36]
                        const uint4* __restrict__ eaPk, const int* __restrict__ srcSorted,
                        const int* __restrict__ offsets, const uint4* __restrict__ Wpk,
                        const float* __restrict__ root,     // [36][24]
                        const float* __restrict__ bias,     // [24]
                        float* __restrict__ hnext) {        // [512][24]
  __shared__ float hS[N_NODES * 37];   // 75776 B
  __shared__ float pAcc[1152];         // 4608 B
  const int tid = threadIdx.x, w = tid >> 6, l = tid & 63;
  const int node = blockIdx.x;
  const int off = offsets[node], cnt = offsets[node + 1] - off;
  const int col = l & 15, crow = (l >> 4) << 2;

  for (int n = tid; n < N_NODES * 36; n += 512) hS[n + n / 36] = hprev[n];
  for (int p = tid; p < 1152; p += 512) pAcc[p] = 0.f;

  f16x8 afr[5][2];
  f32x4 acc[5][2];
#pragma unroll
  for (int jp = 0; jp < 5; jp++) {
    const int tp = w + 8 * jp;
#pragma unroll
    for (int hh = 0; hh < 2; hh++) {
      uint4 wv = make_uint4(0u, 0u, 0u, 0u);
      if (tp < 36 && l < 16) wv = Wpk[(2 * tp + hh) * 16 + l];
      afr[jp][hh] = __builtin_bit_cast(f16x8, wv);
      acc[jp][hh] = (f32x4){0.f, 0.f, 0.f, 0.f};
    }
  }
  __syncthreads();

  const int NG = (cnt + 15) >> 4;
  const f32x4 zero4 = {0.f, 0.f, 0.f, 0.f};
  for (int g = 0; g < NG; g++) {
    const int pos = g * 16 + col;
    const bool v = pos < cnt;
    const int s = v ? srcSorted[off + pos] : 0;
    uint4 bv = make_uint4(0u, 0u, 0u, 0u);
    if (l < 16 && v) bv = eaPk[off + pos];
    const f16x8 bfr = __builtin_bit_cast(f16x8, bv);
    const int sb = s * 37;
#pragma unroll
    for (int jp = 0; jp < 5; jp++) {
      const int tp = w + 8 * jp;
      if (tp < 36) {
        const float hv = hS[sb + tp];   // i = tp, uniform per tile-pair
#pragma unroll
        for (int hh = 0; hh < 2; hh++) {
          f32x4 th = __builtin_amdgcn_mfma_f32_16x16x32_f16(afr[jp][hh], bfr, zero4, 0, 0, 0);
#pragma unroll
          for (int r = 0; r < 4; r++)
            acc[jp][hh][r] = fmaf(fmaxf(th[r], 0.f), hv, acc[jp][hh][r]);
        }
      }
    }
  }

#pragma unroll
  for (int jp = 0; jp < 5; jp++) {
    const int tp = w + 8 * jp;
    if (tp < 36) {
#pragma unroll
      for (int hh = 0; hh < 2; hh++)
#pragma unroll
        for (int r = 0; r < 4; r++) {
          float vv = acc[jp][hh][r];
          vv += __shfl_xor(vv, 1); vv += __shfl_xor(vv, 2);
          vv += __shfl_xor(vv, 4); vv += __shfl_xor(vv, 8);
          if (col == 0) pAcc[tp * 32 + hh * 16 + crow + r] = vv;  // p_pad = i*32+o
        }
    }
  }
  __syncthreads();
  if (tid < 24) {
    const int o = tid;
    float sagg = 0.f;
    for (int i = 0; i < 36; i++) sagg += pAcc[i * 32 + o];
    const float agg = sagg / fmaxf((float)cnt, 1.f);
    float r2 = bias[o];
    for (int i = 0; i < 36; i++) r2 = fmaf(hS[node * 37 + i], root[i * 24 + o], r2);
    hnext[node * 24 + o] = fmaxf(agg + r2, 0.f);
  }
}

// ======== layer 3: IN=24, OUT=5 (8 tiles, 3 i's per tile). Wave-indep groups. ====
__launch_bounds__(512, 4)
__global__ void conv3_k(const float* __restrict__ hprev,    // [512][24]
                        const uint4* __restrict__ eaPk, const int* __restrict__ srcSorted,
                        const int* __restrict__ offsets, const uint4* __restrict__ Wpk,
                        const float* __restrict__ root,     // [24][5]
                        const float* __restrict__ bias,     // [5]
                        float* __restrict__ hnext) {        // [512][5]
  __shared__ float hS[N_NODES * 25];   // 51200 B
  __shared__ float pAcc[8][128];
  const int tid = threadIdx.x, w = tid >> 6, l = tid & 63;
  const int node = blockIdx.x;
  const int off = offsets[node], cnt = offsets[node + 1] - off;
  const int col = l & 15, crow = (l >> 4) << 2;

  for (int n = tid; n < N_NODES * 24; n += 512) hS[n + n / 24] = hprev[n];

  f16x8 afr[8];
  f32x4 acc[8];
#pragma unroll
  for (int t = 0; t < 8; t++) {
    uint4 wv = make_uint4(0u, 0u, 0u, 0u);
    if (l < 16) wv = Wpk[t * 16 + l];
    afr[t] = __builtin_bit_cast(f16x8, wv);
    acc[t] = (f32x4){0.f, 0.f, 0.f, 0.f};
  }
  __syncthreads();

  const int NG = (cnt + 15) >> 4;
  const f32x4 zero4 = {0.f, 0.f, 0.f, 0.f};
  for (int g = w; g < NG; g += 8) {
    const int pos = g * 16 + col;
    const bool v = pos < cnt;
    const int s = v ? srcSorted[off + pos] : 0;
    uint4 bv = make_uint4(0u, 0u, 0u, 0u);
    if (l < 16 && v) bv = eaPk[off + pos];
    const f16x8 bfr = __builtin_bit_cast(f16x8, bv);
    const int sb = s * 25;
#pragma unroll
    for (int t = 0; t < 8; t++) {
      f32x4 th = __builtin_amdgcn_mfma_f32_16x16x32_f16(afr[t], bfr, zero4, 0, 0, 0);
      const float h0 = hS[sb + 3 * t];
      const float h1 = hS[sb + 3 * t + 1];
      const float h2 = hS[sb + 3 * t + 2];
#pragma unroll
      for (int r = 0; r < 4; r++) {
        const int row = crow + r;
        const float hv = (row < 5) ? h0 : ((row < 10) ? h1 : h2);
        acc[t][r] = fmaf(fmaxf(th[r], 0.f), hv, acc[t][r]);
      }
    }
  }
#pragma unroll
  for (int t = 0; t < 8; t++)
#pragma unroll
    for (int r = 0; r < 4; r++) {
      float vv = acc[t][r];
      vv += __shfl_xor(vv, 1); vv += __shfl_xor(vv, 2);
      vv += __shfl_xor(vv, 4); vv += __shfl_xor(vv, 8);
      if (col == 0) pAcc[w][t * 16 + crow + r] = vv;
    }
  __syncthreads();
  if (tid < 128) {
    float s8 = 0.f;
#pragma unroll
    for (int ww = 0; ww < 8; ww++) s8 += pAcc[ww][tid];
    pAcc[0][tid] = s8;
  }
  __syncthreads();
  if (tid < 5) {
    const int o = tid;
    float sagg = 0.f;
    for (int i = 0; i < 24; i++) {
      const int t = i / 3, iloc = i - 3 * t;
      sagg += pAcc[0][t * 16 + iloc * 5 + o];
    }
    const float agg = sagg / fmaxf((float)cnt, 1.f);
    float r2 = bias[o];
    for (int i = 0; i < 24; i++) r2 = fmaf(hS[node * 25 + i], root[i * 5 + o], r2);
    hnext[node * 5 + o] = fmaxf(agg + r2, 0.f);
  }
}

// ---------------- CBT: pairwise L1 over h3 [512, 5] ----------------
__global__ void cbt_k(const float* __restrict__ h3, float* __restrict__ out) {
  __shared__ float sh[N_NODES * 5];
  for (int i = threadIdx.x; i < N_NODES * 5; i += blockDim.x) sh[i] = h3[i];
  __syncthreads();
  const int a = blockIdx.x;
  float ha0 = sh[a * 5 + 0], ha1 = sh[a * 5 + 1], ha2 = sh[a * 5 + 2],
        ha3 = sh[a * 5 + 3], ha4 = sh[a * 5 + 4];
  for (int b = threadIdx.x; b < N_NODES; b += blockDim.x) {
    float s = fabsf(sh[b * 5 + 0] - ha0) + fabsf(sh[b * 5 + 1] - ha1) +
              fabsf(sh[b * 5 + 2] - ha2) + fabsf(sh[b * 5 + 3] - ha3) +
              fabsf(sh[b * 5 + 4] - ha4);
    out[a * N_NODES + b] = s;
  }
}

extern "C" void kernel_launch(void* const* d_in, const int* in_sizes, int n_in,
                              void* d_out, int out_size, void* d_ws, size_t ws_size,
                              hipStream_t stream) {
  const float* x     = (const float*)d_in[0];
  const float* ea    = (const float*)d_in[1];
  const int*   ei    = (const int*)d_in[2];
  const float* W1    = (const float*)d_in[3];
  const float* b1    = (const float*)d_in[4];
  const float* root1 = (const float*)d_in[5];
  const float* bias1 = (const float*)d_in[6];
  const float* W2    = (const float*)d_in[7];
  const float* b2    = (const float*)d_in[8];
  const float* root2 = (const float*)d_in[9];
  const float* bias2 = (const float*)d_in[10];
  const float* W3    = (const float*)d_in[11];
  const float* b3    = (const float*)d_in[12];
  const float* root3 = (const float*)d_in[13];
  const float* bias3 = (const float*)d_in[14];

  const int* src = ei;
  const int* dst = ei + N_EDGES;

  char* ws = (char*)d_ws;
  int* counts    = (int*)(ws + 0);
  int* offsets   = (int*)(ws + 4096);
  int* cursor    = (int*)(ws + 8192);
  uint4* eaPk    = (uint4*)(ws + 16384);                 // 4 MB
  int* srcSorted = (int*)(ws + 16384 + N_EDGES * 16);    // 1 MB
  char* p2       = ws + 16384 + N_EDGES * 20;
  float* h1      = (float*)(p2);                         // [512][36]
  float* h2_     = h1 + N_NODES * 36;                    // [512][24]
  float* h3      = h2_ + N_NODES * 24;                   // [512][5]
  uint4* wpkAll  = (uint4*)(p2 + 256 * 1024);            // 1328 uint4
  uint4* wpk1    = wpkAll;                               // 48
  uint4* wpk2    = wpkAll + 48;                          // 1152
  uint4* wpk3    = wpkAll + 1200;                        // 128

  hipMemsetAsync(counts, 0, N_NODES * sizeof(int), stream);
  hist_k<<<64, 256, 0, stream>>>(dst, counts);
  scan_k<<<1, N_NODES, 0, stream>>>(counts, offsets, cursor);
  scatter3_k<<<N_EDGES / 4096, 512, 0, stream>>>(ea, src, dst, cursor, eaPk, srcSorted);
  packAll2_k<<<6, 256, 0, stream>>>(W1, b1, W2, b2, W3, b3, wpkAll);

  conv1_k<<<N_NODES, 512, 0, stream>>>(x, eaPk, srcSorted, offsets, wpk1, root1, bias1, h1);
  conv2_k<<<N_NODES, 512, 0, stream>>>(h1, eaPk, srcSorted, offsets, wpk2, root2, bias2, h2_);
  conv3_k<<<N_NODES, 512, 0, stream>>>(h2_, eaPk, srcSorted, offsets, wpk3, root3, bias3, h3);

  cbt_k<<<N_NODES, 256, 0, stream>>>(h3, (float*)d_out);
}